// Round 10
// baseline (200.969 us; speedup 1.0000x reference)
//
#include <hip/hip_runtime.h>

// proto-contrastive CE loss via bf16 MFMA.
// R10: persistent 1-block/CU + double-buffered LDS + COUNTED vmcnt pipeline
// (T3/T4, m201 template). Per iter: issue DMA(t+1) -> s_waitcnt vmcnt(9)
// (never 0 in loop) -> raw s_barrier -> compute(t) -> raw s_barrier.
// All bulk loads via global_load_lds (VMEM queue stays pure so compiler
// never inserts a draining vmcnt for a VGPR load).

#define NS 1000000
#define NC 150
#define NCP 160
#define FD 128
#define TS 80                 // samples per tile = 5 waves x 16
#define NT (NS / TS)          // 12500 tiles
#define NBLK 256              // 1 block per CU (LDS-capped)
#define NTHR 320              // 5 waves

static constexpr float INV_T = 1.0f / 0.15f;
static constexpr float MB    = 1.0f / 0.15f;
static constexpr float LOG2E = 1.4426950408889634f;
static constexpr float B2    = -MB * LOG2E;

typedef __attribute__((ext_vector_type(8))) short short8;
typedef __attribute__((ext_vector_type(4))) float f32x4;
typedef unsigned int u32;

#define GLOAD16(g, l) \
    __builtin_amdgcn_global_load_lds((const __attribute__((address_space(1))) u32*)(g), \
                                     (__attribute__((address_space(3))) u32*)(l), 16, 0, 0)

__device__ __forceinline__ unsigned f2bf_u(float x) {
    unsigned u = __builtin_bit_cast(unsigned, x);
    return (u + 0x7fffu + ((u >> 16) & 1u)) >> 16;   // RNE
}

// ---- prep: protos [150][128] f32 -> bf16, padded 160 rows, PRE-SWIZZLED:
//      16B chunk cb of row r stored at chunk position cb ^ (r&7).
__global__ __launch_bounds__(256) void proto_prep(
    const float* __restrict__ protos, u32* __restrict__ dst)  // 40960 B
{
    const int tid = threadIdx.x;
#pragma unroll
    for (int i = 0; i < 10; ++i) {            // 2560 chunks of 16 B
        int c  = i * 256 + tid;
        int r  = c >> 4;
        int cb = c & 15;
        float f[8];
#pragma unroll
        for (int j = 0; j < 8; ++j)
            f[j] = (r < NC) ? protos[r * FD + cb * 8 + j] : 0.0f;
        u32 w[4];
#pragma unroll
        for (int j = 0; j < 4; ++j)
            w[j] = f2bf_u(f[2 * j]) | (f2bf_u(f[2 * j + 1]) << 16);
        u32* out = dst + (r * 64 + ((cb ^ (r & 7)) << 2));
        out[0] = w[0]; out[1] = w[1]; out[2] = w[2]; out[3] = w[3];
    }
}

// LDS layout (bytes):
//   [     0,  40960) protos, pre-swizzled bf16
//   [ 40960, 122880) feature dbuf: parity p at 40960 + p*40960
//   [122880, 123520) label  dbuf: parity p at 122880 + p*320
__global__ __launch_bounds__(NTHR) void proto_ce_mfma(
    const float* __restrict__ feats,
    const int*   __restrict__ labels,
    const u32*   __restrict__ protos_sw,
    double*      __restrict__ partials)
{
    __shared__ __align__(16) char lds[123520];

    const int tid  = threadIdx.x;
    const int lane = tid & 63;
    const int wave = tid >> 6;
    const int col  = lane & 15;     // sample in 16-tile / class row
    const int grp  = lane >> 4;     // k-group

    // ---- stage one 80-sample tile into parity par (9 DMA per thread-wave) ----
    auto stage = [&](int tile, int par) {
        const char* fs = (const char*)feats + (size_t)tile * (TS * FD * 4);
        char* fb = lds + 40960 + par * 40960;
#pragma unroll
        for (int j = 0; j < 8; ++j) {
            int c = j * NTHR + tid;          // 0..2559 16B chunks
            int r = c >> 5;                  // sample row 0..79
            int x = c & 31;                  // chunk in 512B row
            GLOAD16(fs + r * 512 + ((x ^ (r & 7)) << 4), fb + c * 16);
        }
        // labels: 320 B; every wave issues (vmcnt uniform), lanes 0..19 active
        if (lane < 20)
            GLOAD16((const char*)labels + (size_t)tile * (TS * 4) + lane * 16,
                    lds + 122880 + par * 320 + lane * 16);
    };

    // ---- prologue: protos (8 chunks/thread) + tile0, drain, barrier ----
    {
        const char* ps = (const char*)protos_sw;
#pragma unroll
        for (int i = 0; i < 8; ++i) {
            int c = i * NTHR + tid;
            GLOAD16(ps + c * 16, lds + c * 16);
        }
    }
    stage(blockIdx.x, 0);
    asm volatile("s_waitcnt vmcnt(0)" ::: "memory");
    __builtin_amdgcn_s_barrier();

    // proto LDS read addressing (verified R2..R9):
    const int sw  = (col & 7) << 4;
    const int a0  = col * 256 + ((grp * 16) ^ (sw & 0x30));
    const int ahi = sw & 0x40;
    const int s3  = col & 7;
    const int lrel = -grp * 4;
    const int vcnt = 6 - grp * 4;
    const int frow = (wave * 16 + col) * 512;

    float loss_acc = 0.0f;
    int iter = 0;

    for (int t = blockIdx.x; t < NT; t += NBLK, ++iter) {
        const int  par  = iter & 1;
        const bool more = (t + NBLK) < NT;

        if (more) {
            stage(t + NBLK, par ^ 1);
            asm volatile("s_waitcnt vmcnt(9)" ::: "memory");   // t's 9 landed
        } else {
            asm volatile("s_waitcnt vmcnt(0)" ::: "memory");
        }
        __builtin_amdgcn_s_barrier();

        // ---- compute tile t from parity par ----
        const char* fb = lds + 40960 + par * 40960;
        const int*  lb = (const int*)(lds + 122880 + par * 320);
        const char* f0 = fb + frow + (((grp << 1) ^ s3) << 4);
        const char* f1 = fb + frow + ((((grp << 1) | 1) ^ s3) << 4);

        const int lbl = lb[wave * 16 + col];

        f32x4 acc[10];
#pragma unroll
        for (int i = 0; i < 10; ++i) acc[i] = (f32x4){0.f, 0.f, 0.f, 0.f};

        float ssq = 0.0f;
#pragma unroll
        for (int kb = 0; kb < 4; ++kb) {
            float4 A  = *(const float4*)(f0 + kb * 128);
            float4 Bv = *(const float4*)(f1 + kb * 128);
            ssq += A.x * A.x + A.y * A.y + A.z * A.z + A.w * A.w;
            ssq += Bv.x * Bv.x + Bv.y * Bv.y + Bv.z * Bv.z + Bv.w * Bv.w;

            short8 bfr;
            bfr[0] = (short)f2bf_u(A.x);  bfr[1] = (short)f2bf_u(A.y);
            bfr[2] = (short)f2bf_u(A.z);  bfr[3] = (short)f2bf_u(A.w);
            bfr[4] = (short)f2bf_u(Bv.x); bfr[5] = (short)f2bf_u(Bv.y);
            bfr[6] = (short)f2bf_u(Bv.z); bfr[7] = (short)f2bf_u(Bv.w);

            const char* ap = lds + (a0 + ((kb * 64) ^ ahi));
#pragma unroll
            for (int tt = 0; tt < 10; ++tt) {
                short8 af = *(const short8*)(ap + tt * 4096);
                acc[tt] = __builtin_amdgcn_mfma_f32_16x16x32_bf16(af, bfr, acc[tt], 0, 0, 0);
            }
        }

        ssq += __shfl_xor(ssq, 16, 64);
        ssq += __shfl_xor(ssq, 32, 64);
        const float scl = rsqrtf(fmaxf(ssq, 1e-24f));

        const float k2 = scl * (INV_T * LOG2E);
        const int   lm = lbl + lrel;
        float s0 = 0.f, s1 = 0.f, s2 = 0.f, s3v = 0.f;
        float pick = 0.0f;
#pragma unroll
        for (int tt = 0; tt < 10; ++tt) {
#pragma unroll
            for (int r = 0; r < 4; ++r) {
                float a = acc[tt][r];
                float e = exp2f(fmaf(a, k2, B2));
                if (tt < 9) {
                    if      (r == 0) s0 += e;
                    else if (r == 1) s1 += e;
                    else if (r == 2) s2 += e;
                    else             s3v += e;
                } else {
                    s0 += (r < vcnt) ? e : 0.0f;   // mask classes 150..159
                }
                pick = (tt * 16 + r == lm) ? a : pick;
            }
        }
        float ssum = (s0 + s1) + (s2 + s3v);
        ssum += __shfl_xor(ssum, 16, 64);
        ssum += __shfl_xor(ssum, 32, 64);
        pick += __shfl_xor(pick, 16, 64);
        pick += __shfl_xor(pick, 32, 64);

        loss_acc += __logf(ssum) + MB - pick * (scl * INV_T);

        __builtin_amdgcn_s_barrier();   // all reads of parity par done
    }

    // sum 16 samples (grp copies identical; reduce within 16-lane group)
    loss_acc += __shfl_xor(loss_acc, 1, 64);
    loss_acc += __shfl_xor(loss_acc, 2, 64);
    loss_acc += __shfl_xor(loss_acc, 4, 64);
    loss_acc += __shfl_xor(loss_acc, 8, 64);
    if (lane == 0)
        atomicAdd(&partials[(blockIdx.x * 5 + wave) & 255], (double)loss_acc);
}

__global__ __launch_bounds__(256) void proto_ce_final(
    const double* __restrict__ partials, float* __restrict__ out)
{
    const int tid = threadIdx.x;
    double v = partials[tid];
#pragma unroll
    for (int off = 32; off > 0; off >>= 1)
        v += __shfl_down(v, off, 64);
    __shared__ double w[4];
    if ((tid & 63) == 0) w[tid >> 6] = v;
    __syncthreads();
    if (tid == 0)
        out[0] = (float)((w[0] + w[1] + w[2] + w[3]) * (1.0 / (double)NS));
}

extern "C" void kernel_launch(void* const* d_in, const int* in_sizes, int n_in,
                              void* d_out, int out_size, void* d_ws, size_t ws_size,
                              hipStream_t stream)
{
    const float* feats  = (const float*)d_in[0];
    const int*   labels = (const int*)d_in[1];
    const float* protos = (const float*)d_in[2];

    u32* protos_sw = (u32*)d_ws;                                  // 40960 B
    double* partials = (double*)((char*)d_ws + NCP * FD * 2);     // 2048 B

    (void)hipMemsetAsync(partials, 0, 256 * sizeof(double), stream);
    proto_prep<<<1, 256, 0, stream>>>(protos, protos_sw);
    proto_ce_mfma<<<NBLK, NTHR, 0, stream>>>(feats, labels, protos_sw, partials);
    proto_ce_final<<<1, 256, 0, stream>>>(partials, (float*)d_out);
}